// Round 16
// baseline (325.197 us; speedup 1.0000x reference)
//
#include <hip/hip_runtime.h>

// ---------- types ----------
typedef __attribute__((ext_vector_type(8))) short  s8v;    // 8 bf16 (as shorts) = 4 VGPR
typedef __attribute__((ext_vector_type(8))) unsigned short us8;
typedef __attribute__((ext_vector_type(4))) unsigned short us4;
typedef __attribute__((ext_vector_type(4))) float  f4v;    // MFMA accumulator

// float -> bf16 round-to-nearest-even (inputs are finite)
__device__ __forceinline__ unsigned short f2bf(float f) {
  unsigned int u = __builtin_bit_cast(unsigned int, f);
  u += 0x7fffu + ((u >> 16) & 1u);
  return (unsigned short)(u >> 16);
}

// async global->LDS, 16B per lane; offset arg must stay 0 (only verified mode).
__device__ __forceinline__ void gll16(const void* g, void* l) {
  __builtin_amdgcn_global_load_lds(
      (const __attribute__((address_space(1))) unsigned int*)g,
      (__attribute__((address_space(3))) unsigned int*)l, 16, 0, 0);
}

// ---------- kernel 1: x fp32 -> bf16 ----------
__global__ __launch_bounds__(256) void cast_bf16(const float* __restrict__ in,
                                                 unsigned short* __restrict__ out) {
  const size_t i = (size_t)blockIdx.x * 256 + threadIdx.x;
  const f4v* p = (const f4v*)in;
  f4v a = p[2 * i];
  f4v b = p[2 * i + 1];
  us8 r;
  r[0] = f2bf(a[0]); r[1] = f2bf(a[1]); r[2] = f2bf(a[2]); r[3] = f2bf(a[3]);
  r[4] = f2bf(b[0]); r[5] = f2bf(b[1]); r[6] = f2bf(b[2]); r[7] = f2bf(b[3]);
  *(us8*)&out[i * 8] = r;
}

// ---------- kernel 2: T[(o1i1)*256+(o2i2)][r2] = sum_r1 c0*c1, bf16 out ----------
__global__ __launch_bounds__(256) void contract1b(const float* __restrict__ c0,
                                                  const float* __restrict__ c1,
                                                  unsigned short* __restrict__ T) {
  const int idx = blockIdx.x * 256 + threadIdx.x;   // 1,048,576
  const int r2q = idx & 15;
  const int oi2 = (idx >> 4) & 255;
  const int oi1 = idx >> 12;
  const float* c0p = c0 + oi1 * 64;
  const float* c1p = c1 + oi2 * 64 + r2q * 4;
  f4v s = (f4v)0.f;
#pragma unroll 8
  for (int r1 = 0; r1 < 64; ++r1) {
    const float t = c0p[r1];
    const f4v v = *(const f4v*)(c1p + r1 * 16384);
    s[0] = fmaf(t, v[0], s[0]); s[1] = fmaf(t, v[1], s[1]);
    s[2] = fmaf(t, v[2], s[2]); s[3] = fmaf(t, v[3], s[3]);
  }
  us4 o;
  o[0] = f2bf(s[0]); o[1] = f2bf(s[1]); o[2] = f2bf(s[2]); o[3] = f2bf(s[3]);
  *(us4*)&T[(size_t)idx * 4] = o;
}

// ---------- kernel 2b: c2t[n=o3*16+i3][k=r2] bf16 = c2[r2][n] ----------
__global__ __launch_bounds__(256) void transc2(const float* __restrict__ c2,
                                               unsigned short* __restrict__ c2t) {
  const int n = blockIdx.x * 16 + (threadIdx.x >> 4);
  const int j = threadIdx.x & 15;
  us4 o;
#pragma unroll
  for (int q = 0; q < 4; ++q) o[q] = f2bf(c2[(j * 4 + q) * 256 + n]);
  *(us4*)&c2t[(size_t)n * 64 + j * 4] = o;
}

// ---------- kernel 3: buildW3 — 256x256x64 MFMA mini-GEMM per (o1,o2) ----------
__global__ __launch_bounds__(256) void buildW3(const unsigned short* __restrict__ T,
                                               const unsigned short* __restrict__ c2t,
                                               unsigned short* __restrict__ W) {
  __shared__ unsigned short sT[16384];  // 32 KB [m 256][k 64] swizzled
  __shared__ unsigned short sC[16384];  // 32 KB [n 256][k 64] swizzled

  const int tid = threadIdx.x;
  const int o1 = blockIdx.x >> 4, o2 = blockIdx.x & 15;

#pragma unroll
  for (int j = 0; j < 8; ++j) {
    const int c = j * 256 + tid;
    const int m = c >> 3, sl = c & 7;
    const int dst = m * 64 + ((sl ^ (m & 7)) << 3);
    *(us8*)&sT[dst] = *(const us8*)(T + (size_t)(o1 * 16 + (m >> 4)) * 16384 +
                                    (o2 * 16 + (m & 15)) * 64 + sl * 8);
    *(us8*)&sC[dst] = *(const us8*)(c2t + (size_t)m * 64 + sl * 8);
  }
  __syncthreads();

  const int lane = tid & 63, wid = tid >> 6;
  const int fr = lane & 15, ks = lane >> 4;
  const int f7 = fr & 7;
  const int sx0 = ((ks ^ f7) << 3);
  const int sx1 = (((4 + ks) ^ f7) << 3);

  s8v a[4][2];
#pragma unroll
  for (int mi = 0; mi < 4; ++mi) {
    const unsigned short* p = &sT[(wid * 64 + mi * 16 + fr) * 64];
    a[mi][0] = *(const s8v*)(p + sx0);
    a[mi][1] = *(const s8v*)(p + sx1);
  }
#pragma unroll
  for (int nt = 0; nt < 16; ++nt) {
    const unsigned short* p = &sC[(nt * 16 + fr) * 64];
    const s8v b0 = *(const s8v*)(p + sx0);
    const s8v b1 = *(const s8v*)(p + sx1);
#pragma unroll
    for (int mi = 0; mi < 4; ++mi) {
      f4v acc = (f4v)0.f;
      acc = __builtin_amdgcn_mfma_f32_16x16x32_bf16(a[mi][0], b0, acc, 0, 0, 0);
      acc = __builtin_amdgcn_mfma_f32_16x16x32_bf16(a[mi][1], b1, acc, 0, 0, 0);
      unsigned short* wp = W + (size_t)(o1 * 256 + o2 * 16 + nt) * 4096 +
                           (wid * 4 + mi) * 256 + fr;
#pragma unroll
      for (int r = 0; r < 4; ++r) wp[(ks * 4 + r) * 16] = f2bf(acc[r]);
    }
  }
}

// ---------- kernel 4: 256x256-tile GEMM, fully-cross-phase 8-phase pipeline ----------
// A[M][K], B[N][K] bf16, C[M][N] fp32. M=8192, N=4096, K=4096.
// buf0=even K-tiles @0, buf1=odd @32768. Per buf: Alo@0,Ahi@8192,Blo@16384,Bhi@24576.
// Swizzle slot^row&7 both sides (0 conflicts, proven R9-R14).
// EVERY MFMA consumes registers read in a PRIOR phase (8 barriers/iter, no extra
// phases): publication VMW moved to P3/P7-end so the next tile's Q00 operands are
// read inside P4/P8 (post-pub-barrier, pinned by the VMW "memory" clobber),
// consumed next phase. Quadrant order Q00,Q01,Q10,Q11.
// Reads: P8'->P1, P1->P2(bH), P2->P3,P4(aHi), P4->P5(aLo,bL c1), P5->P6, P6->P7,P8.
// Stages: P1:Bhi(c1) P2:Alo(c0+2) P3:Blo(c0+2) P4:Ahi(c0+2) P5:Bhi(c0+2)
//         P6:Alo(c1+2) P7:Blo(c1+2) P8:Ahi(c1+2).
// VMW(4)@P3-end lands all c1 (2 newest STG fly); VMW(4)@P7-end lands all c0+2.
// WAR audit: every staged region's last reader lgkm-completes >=2 barriers prior.

#define BAR() __builtin_amdgcn_s_barrier()
#define VMW(N) asm volatile("s_waitcnt vmcnt(" #N ")" ::: "memory")

template<int MQ, int NQ>
__device__ __forceinline__ void mmq(f4v (&acc)[8][4], const s8v (&a)[4][2], const s8v (&b)[2][2]) {
  __builtin_amdgcn_s_setprio(1);
#pragma unroll
  for (int mi = 0; mi < 4; ++mi)
#pragma unroll
    for (int ni = 0; ni < 2; ++ni)
#pragma unroll
      for (int q = 0; q < 2; ++q)
        acc[MQ * 4 + mi][NQ * 2 + ni] = __builtin_amdgcn_mfma_f32_16x16x32_bf16(
            a[mi][q], b[ni][q], acc[MQ * 4 + mi][NQ * 2 + ni], 0, 0, 0);
  __builtin_amdgcn_s_setprio(0);
}

__global__ __launch_bounds__(512, 2) void gemm8(const unsigned short* __restrict__ A,
                                                const unsigned short* __restrict__ B,
                                                float* __restrict__ C) {
  constexpr int N = 4096, K = 4096;
  constexpr int NT = K / 64;
  constexpr int NITER = NT / 2;     // 32 iters, 2 K-tiles each
  constexpr int NXT = N / 256;

  __shared__ unsigned short lds[65536];   // 128 KiB

  const int tid  = threadIdx.x;
  const int lane = tid & 63;
  const int wid  = tid >> 6;
  const int wm   = wid >> 2;
  const int wn   = wid & 3;

  const int cpx = (int)gridDim.x >> 3;
  const int wg  = ((int)blockIdx.x & 7) * cpx + ((int)blockIdx.x >> 3);
  const long bm = (long)(wg / NXT) * 256;
  const long bn = (long)(wg % NXT) * 256;

  const int srow = tid >> 3;
  const int scol = ((tid & 7) ^ (srow & 7)) * 8;
  const unsigned short* gA = A + (bm + srow) * (size_t)K + scol;
  const unsigned short* gB = B + (bn + srow) * (size_t)K + scol;
  const size_t half64 = 64 * (size_t)K;
  const size_t k128   = 128 * (size_t)K;

#define STG(gp, koff, ldsU) do {                                  \
    const unsigned short* g_ = (gp) + (koff);                     \
    gll16(g_,          &lds[(ldsU) + tid * 8]);                   \
    gll16(g_ + half64, &lds[(ldsU) + 4096 + tid * 8]);            \
  } while (0)

  const int fr = lane & 15;
  const int ks = lane >> 4;
  const int f7 = fr & 7;
  const int sx0 = (ks ^ f7) * 8;
  const int sx1 = ((ks | 4) ^ f7) * 8;
  const int arow = (wm * 64 + fr) * 64;
  const int brow = (wn * 32 + fr) * 64;

#define RDA(dst, MQ, bufU) do {                                              \
    const unsigned short* p_ = &lds[(bufU) + (MQ) * 8192 + arow];            \
    dst[0][0] = *(const s8v*)(p_ + sx0);        dst[0][1] = *(const s8v*)(p_ + sx1); \
    dst[1][0] = *(const s8v*)(p_ + 1024 + sx0); dst[1][1] = *(const s8v*)(p_ + 1024 + sx1); \
    dst[2][0] = *(const s8v*)(p_ + 2048 + sx0); dst[2][1] = *(const s8v*)(p_ + 2048 + sx1); \
    dst[3][0] = *(const s8v*)(p_ + 3072 + sx0); dst[3][1] = *(const s8v*)(p_ + 3072 + sx1); \
  } while (0)
#define RDB(dst, NQ, bufU) do {                                              \
    const unsigned short* p_ = &lds[(bufU) + 16384 + (NQ) * 8192 + brow];    \
    dst[0][0] = *(const s8v*)(p_ + sx0);        dst[0][1] = *(const s8v*)(p_ + sx1); \
    dst[1][0] = *(const s8v*)(p_ + 1024 + sx0); dst[1][1] = *(const s8v*)(p_ + 1024 + sx1); \
  } while (0)

  f4v acc[8][4];
#pragma unroll
  for (int m = 0; m < 8; ++m)
#pragma unroll
    for (int n = 0; n < 4; ++n) acc[m][n] = (f4v)0.0f;

  // prologue: c0 all 4 halves (buf0) + c1's Alo,Blo,Ahi (buf1). VMW(6) lands c0.
  STG(gA,        0, 0);
  STG(gA + k128, 0, 8192);
  STG(gB,        0, 16384);
  STG(gB + k128, 0, 24576);
  STG(gA,        64, 32768);          // Alo(c1)
  STG(gB,        64, 32768 + 16384);  // Blo(c1)
  STG(gA + k128, 64, 32768 + 8192);   // Ahi(c1)
  VMW(6);
  BAR();

  s8v a0[4][2], a1[4][2], b0[2][2], b1[2][2];
  RDA(a0, 0, 0);    // aLo(c0)  ("P8 of iter -1")
  RDB(b0, 0, 0);    // bL(c0)

  for (int i = 0; i < NITER; ++i) {
    const long w2 = (i == NITER - 1) ? -128L : 0L;   // wrap c0+2 dummy stages
    const long w3 = (i == NITER - 1) ? -192L : 0L;   // wrap c1+2 dummy stages
    // ---- P1: rd bH(c0); STG Bhi(c1); MM Q00(a0,b0) ----
    RDB(b1, 1, 0);
    STG(gB + k128, 64, 32768 + 24576);
    mmq<0, 0>(acc, a0, b0);
    BAR();
    // ---- P2: rd a1<-Ahi(c0); STG Alo(c0+2); MM Q01(a0,b1) ----
    RDA(a1, 1, 0);
    STG(gA, 128 + w2, 0);
    mmq<0, 1>(acc, a0, b1);
    BAR();
    // ---- P3: STG Blo(c0+2); MM Q10(a1,b0); VMW(4) pub c1 ----
    STG(gB, 128 + w2, 16384);
    mmq<1, 0>(acc, a1, b0);
    VMW(4); BAR();
    // ---- P4: rd a0,b0<-c1 (post-pub); STG Ahi(c0+2); MM Q11(a1,b1) ----
    RDA(a0, 0, 32768);
    RDB(b0, 0, 32768);
    STG(gA + k128, 128 + w2, 8192);
    mmq<1, 1>(acc, a1, b1);
    BAR();
    // ---- P5: rd bH(c1); STG Bhi(c0+2); MM Q00(a0,b0) ----
    RDB(b1, 1, 32768);
    STG(gB + k128, 128 + w2, 24576);
    mmq<0, 0>(acc, a0, b0);
    BAR();
    // ---- P6: rd a1<-Ahi(c1); STG Alo(c1+2); MM Q01(a0,b1) ----
    RDA(a1, 1, 32768);
    STG(gA, 192 + w3, 32768);
    mmq<0, 1>(acc, a0, b1);
    BAR();
    // ---- P7: STG Blo(c1+2); MM Q10(a1,b0); VMW(4) pub c0+2 ----
    STG(gB, 192 + w3, 32768 + 16384);
    mmq<1, 0>(acc, a1, b0);
    VMW(4); BAR();
    // ---- P8: rd a0,b0<-c0+2 (post-pub); STG Ahi(c1+2); MM Q11(a1,b1) ----
    RDA(a0, 0, 0);
    RDB(b0, 0, 0);
    STG(gA + k128, 192 + w3, 32768 + 8192);
    mmq<1, 1>(acc, a1, b1);
    BAR();

    gA += 128; gB += 128;
  }
  VMW(0);          // drain remaining dummy prefetches

  // ---- epilogue: row = bm + mq*128 + wm*64 + mi*16 + ks*4 + r ; col = bn + nq*128 + wn*32 + ni*16 + fr
#pragma unroll
  for (int mq = 0; mq < 2; ++mq)
#pragma unroll
    for (int mi = 0; mi < 4; ++mi)
#pragma unroll
      for (int nq = 0; nq < 2; ++nq)
#pragma unroll
        for (int ni = 0; ni < 2; ++ni) {
          const size_t row0 = bm + mq * 128 + wm * 64 + mi * 16 + ks * 4;
          const size_t col  = bn + nq * 128 + wn * 32 + ni * 16 + fr;
          float* cp = C + row0 * (size_t)N + col;
          f4v v = acc[mq * 4 + mi][nq * 2 + ni];
          cp[0] = v[0]; cp[N] = v[1]; cp[2 * (size_t)N] = v[2]; cp[3 * (size_t)N] = v[3];
        }
#undef STG
#undef RDA
#undef RDB
}

// ---------- launch ----------
extern "C" void kernel_launch(void* const* d_in, const int* in_sizes, int n_in,
                              void* d_out, int out_size, void* d_ws, size_t ws_size,
                              hipStream_t stream) {
  const float* x  = (const float*)d_in[0];   // [8192,4096]
  const float* c0 = (const float*)d_in[1];   // [1,16,16,64]
  const float* c1 = (const float*)d_in[2];   // [64,16,16,64]
  const float* c2 = (const float*)d_in[3];   // [64,16,16,1]
  float* out = (float*)d_out;                // [8192,4096] fp32

  char* ws = (char*)d_ws;
  unsigned short* T   = (unsigned short*)ws;                      // 8 MB  bf16
  unsigned short* c2t = (unsigned short*)(ws + (8u << 20));       // 32 KB bf16
  unsigned short* Wb  = (unsigned short*)(ws + (16u << 20));      // 32 MB bf16
  unsigned short* xb  = (unsigned short*)(ws + (48u << 20));      // 64 MB bf16

  hipLaunchKernelGGL(cast_bf16,  dim3(16384), dim3(256), 0, stream, x, xb);
  hipLaunchKernelGGL(contract1b, dim3(4096),  dim3(256), 0, stream, c0, c1, T);
  hipLaunchKernelGGL(transc2,    dim3(16),    dim3(256), 0, stream, c2, c2t);
  hipLaunchKernelGGL(buildW3,    dim3(256),   dim3(256), 0, stream, T, c2t, Wb);
  hipLaunchKernelGGL(gemm8,      dim3(512),   dim3(512), 0, stream, xb, Wb, out);
}

// Round 17
// 308.181 us; speedup vs baseline: 1.0552x; 1.0552x over previous
//
#include <hip/hip_runtime.h>

// ---------- types ----------
typedef __attribute__((ext_vector_type(8))) short  s8v;    // 8 bf16 (as shorts) = 4 VGPR
typedef __attribute__((ext_vector_type(8))) unsigned short us8;
typedef __attribute__((ext_vector_type(4))) unsigned short us4;
typedef __attribute__((ext_vector_type(4))) float  f4v;    // MFMA accumulator

// float -> bf16 round-to-nearest-even (inputs are finite)
__device__ __forceinline__ unsigned short f2bf(float f) {
  unsigned int u = __builtin_bit_cast(unsigned int, f);
  u += 0x7fffu + ((u >> 16) & 1u);
  return (unsigned short)(u >> 16);
}

// async global->LDS, 16B per lane; offset arg must stay 0 (only verified mode).
__device__ __forceinline__ void gll16(const void* g, void* l) {
  __builtin_amdgcn_global_load_lds(
      (const __attribute__((address_space(1))) unsigned int*)g,
      (__attribute__((address_space(3))) unsigned int*)l, 16, 0, 0);
}

// ---------- kernel 1: x fp32 -> bf16 ----------
__global__ __launch_bounds__(256) void cast_bf16(const float* __restrict__ in,
                                                 unsigned short* __restrict__ out) {
  const size_t i = (size_t)blockIdx.x * 256 + threadIdx.x;
  const f4v* p = (const f4v*)in;
  f4v a = p[2 * i];
  f4v b = p[2 * i + 1];
  us8 r;
  r[0] = f2bf(a[0]); r[1] = f2bf(a[1]); r[2] = f2bf(a[2]); r[3] = f2bf(a[3]);
  r[4] = f2bf(b[0]); r[5] = f2bf(b[1]); r[6] = f2bf(b[2]); r[7] = f2bf(b[3]);
  *(us8*)&out[i * 8] = r;
}

// ---------- kernel 2: T[(o1i1)*256+(o2i2)][r2] = sum_r1 c0*c1, bf16 out ----------
__global__ __launch_bounds__(256) void contract1b(const float* __restrict__ c0,
                                                  const float* __restrict__ c1,
                                                  unsigned short* __restrict__ T) {
  const int idx = blockIdx.x * 256 + threadIdx.x;   // 1,048,576
  const int r2q = idx & 15;
  const int oi2 = (idx >> 4) & 255;
  const int oi1 = idx >> 12;
  const float* c0p = c0 + oi1 * 64;
  const float* c1p = c1 + oi2 * 64 + r2q * 4;
  f4v s = (f4v)0.f;
#pragma unroll 8
  for (int r1 = 0; r1 < 64; ++r1) {
    const float t = c0p[r1];
    const f4v v = *(const f4v*)(c1p + r1 * 16384);
    s[0] = fmaf(t, v[0], s[0]); s[1] = fmaf(t, v[1], s[1]);
    s[2] = fmaf(t, v[2], s[2]); s[3] = fmaf(t, v[3], s[3]);
  }
  us4 o;
  o[0] = f2bf(s[0]); o[1] = f2bf(s[1]); o[2] = f2bf(s[2]); o[3] = f2bf(s[3]);
  *(us4*)&T[(size_t)idx * 4] = o;
}

// ---------- kernel 2b: c2t[n=o3*16+i3][k=r2] bf16 = c2[r2][n] ----------
__global__ __launch_bounds__(256) void transc2(const float* __restrict__ c2,
                                               unsigned short* __restrict__ c2t) {
  const int n = blockIdx.x * 16 + (threadIdx.x >> 4);
  const int j = threadIdx.x & 15;
  us4 o;
#pragma unroll
  for (int q = 0; q < 4; ++q) o[q] = f2bf(c2[(j * 4 + q) * 256 + n]);
  *(us4*)&c2t[(size_t)n * 64 + j * 4] = o;
}

// ---------- kernel 3: buildW3 — 256x256x64 MFMA mini-GEMM per (o1,o2) ----------
__global__ __launch_bounds__(256) void buildW3(const unsigned short* __restrict__ T,
                                               const unsigned short* __restrict__ c2t,
                                               unsigned short* __restrict__ W) {
  __shared__ unsigned short sT[16384];  // 32 KB [m 256][k 64] swizzled
  __shared__ unsigned short sC[16384];  // 32 KB [n 256][k 64] swizzled

  const int tid = threadIdx.x;
  const int o1 = blockIdx.x >> 4, o2 = blockIdx.x & 15;

#pragma unroll
  for (int j = 0; j < 8; ++j) {
    const int c = j * 256 + tid;
    const int m = c >> 3, sl = c & 7;
    const int dst = m * 64 + ((sl ^ (m & 7)) << 3);
    *(us8*)&sT[dst] = *(const us8*)(T + (size_t)(o1 * 16 + (m >> 4)) * 16384 +
                                    (o2 * 16 + (m & 15)) * 64 + sl * 8);
    *(us8*)&sC[dst] = *(const us8*)(c2t + (size_t)m * 64 + sl * 8);
  }
  __syncthreads();

  const int lane = tid & 63, wid = tid >> 6;
  const int fr = lane & 15, ks = lane >> 4;
  const int f7 = fr & 7;
  const int sx0 = ((ks ^ f7) << 3);
  const int sx1 = (((4 + ks) ^ f7) << 3);

  s8v a[4][2];
#pragma unroll
  for (int mi = 0; mi < 4; ++mi) {
    const unsigned short* p = &sT[(wid * 64 + mi * 16 + fr) * 64];
    a[mi][0] = *(const s8v*)(p + sx0);
    a[mi][1] = *(const s8v*)(p + sx1);
  }
#pragma unroll
  for (int nt = 0; nt < 16; ++nt) {
    const unsigned short* p = &sC[(nt * 16 + fr) * 64];
    const s8v b0 = *(const s8v*)(p + sx0);
    const s8v b1 = *(const s8v*)(p + sx1);
#pragma unroll
    for (int mi = 0; mi < 4; ++mi) {
      f4v acc = (f4v)0.f;
      acc = __builtin_amdgcn_mfma_f32_16x16x32_bf16(a[mi][0], b0, acc, 0, 0, 0);
      acc = __builtin_amdgcn_mfma_f32_16x16x32_bf16(a[mi][1], b1, acc, 0, 0, 0);
      unsigned short* wp = W + (size_t)(o1 * 256 + o2 * 16 + nt) * 4096 +
                           (wid * 4 + mi) * 256 + fr;
#pragma unroll
      for (int r = 0; r < 4; ++r) wp[(ks * 4 + r) * 16] = f2bf(acc[r]);
    }
  }
}

// ---------- kernel 4: 256x256-tile GEMM, R13 body + WAR-earliest stages + vmcnt(6) ----------
// A[M][K], B[N][K] bf16, C[M][N] fp32. M=8192, N=4096, K=4096.
// buf0=even K-tiles @0, buf1=odd @32768. Per buf: Alo@0,Ahi@8192,Blo@16384,Bhi@24576.
// Swizzle slot^row&7 both sides (0 conflicts, proven).
// Read/MFMA body = R13 (best): P1-pre {aLo,bL,bH}; P2-post aHi; MMs Q00,Q01,Q10,Q11.
// Stage timing = WAR-earliest (region free 1 barrier after the barrier following its
// last consuming MFMA's lgkm-wait):  P1:Ahi(c1)  P3:Alo+Blo(c0+2)  P4:Bhi(c0+2)
// P5:Ahi(c0+2)  P7:Alo+Blo(c1+2)  P8:Bhi(c1+2).
// VMW(6) at P4/P8 (m201 depth): queue-walk (14 outstanding at each VMW) shows
// VMW(6)@P4 drains exactly the 8 c1 loads (youngest flight = 3 phases > 900cy HBM);
// VMW(6)@P8 drains exactly c0+2 (4-phase flight). Prologue leaves {Alo,Blo,Bhi}(c1)
// = 6 in flight, matching steady state.

#define SBAR() do { asm volatile("" ::: "memory"); __builtin_amdgcn_s_barrier(); asm volatile("" ::: "memory"); } while (0)
#define VMW(N) asm volatile("s_waitcnt vmcnt(" #N ")" ::: "memory")

template<int MQ, int NQ>
__device__ __forceinline__ void mmq(f4v (&acc)[8][4], const s8v (&a)[4][2], const s8v (&b)[2][2]) {
  __builtin_amdgcn_s_setprio(1);
#pragma unroll
  for (int mi = 0; mi < 4; ++mi)
#pragma unroll
    for (int ni = 0; ni < 2; ++ni)
#pragma unroll
      for (int q = 0; q < 2; ++q)
        acc[MQ * 4 + mi][NQ * 2 + ni] = __builtin_amdgcn_mfma_f32_16x16x32_bf16(
            a[mi][q], b[ni][q], acc[MQ * 4 + mi][NQ * 2 + ni], 0, 0, 0);
  __builtin_amdgcn_s_setprio(0);
}

__global__ __launch_bounds__(512, 2) void gemm8(const unsigned short* __restrict__ A,
                                                const unsigned short* __restrict__ B,
                                                float* __restrict__ C) {
  constexpr int N = 4096, K = 4096;
  constexpr int NT = K / 64;
  constexpr int NITER = NT / 2;     // 32 iters, 2 K-tiles each
  constexpr int NXT = N / 256;

  __shared__ unsigned short lds[65536];   // 128 KiB

  const int tid  = threadIdx.x;
  const int lane = tid & 63;
  const int wid  = tid >> 6;
  const int wm   = wid >> 2;
  const int wn   = wid & 3;

  const int cpx = (int)gridDim.x >> 3;
  const int wg  = ((int)blockIdx.x & 7) * cpx + ((int)blockIdx.x >> 3);
  const long bm = (long)(wg / NXT) * 256;
  const long bn = (long)(wg % NXT) * 256;

  const int srow = tid >> 3;
  const int scol = ((tid & 7) ^ (srow & 7)) * 8;
  const unsigned short* gA = A + (bm + srow) * (size_t)K + scol;
  const unsigned short* gB = B + (bn + srow) * (size_t)K + scol;
  const size_t half64 = 64 * (size_t)K;
  const size_t k128   = 128 * (size_t)K;

#define STG(gp, koff, ldsU) do {                                  \
    const unsigned short* g_ = (gp) + (koff);                     \
    gll16(g_,          &lds[(ldsU) + tid * 8]);                   \
    gll16(g_ + half64, &lds[(ldsU) + 4096 + tid * 8]);            \
  } while (0)

  const int fr = lane & 15;
  const int ks = lane >> 4;
  const int f7 = fr & 7;
  const int sx0 = (ks ^ f7) * 8;
  const int sx1 = ((ks | 4) ^ f7) * 8;
  const int arow = (wm * 64 + fr) * 64;
  const int brow = (wn * 32 + fr) * 64;

#define RDA(dst, MQ, bufU) do {                                              \
    const unsigned short* p_ = &lds[(bufU) + (MQ) * 8192 + arow];            \
    dst[0][0] = *(const s8v*)(p_ + sx0);        dst[0][1] = *(const s8v*)(p_ + sx1); \
    dst[1][0] = *(const s8v*)(p_ + 1024 + sx0); dst[1][1] = *(const s8v*)(p_ + 1024 + sx1); \
    dst[2][0] = *(const s8v*)(p_ + 2048 + sx0); dst[2][1] = *(const s8v*)(p_ + 2048 + sx1); \
    dst[3][0] = *(const s8v*)(p_ + 3072 + sx0); dst[3][1] = *(const s8v*)(p_ + 3072 + sx1); \
  } while (0)
#define RDB(dst, NQ, bufU) do {                                              \
    const unsigned short* p_ = &lds[(bufU) + 16384 + (NQ) * 8192 + brow];    \
    dst[0][0] = *(const s8v*)(p_ + sx0);        dst[0][1] = *(const s8v*)(p_ + sx1); \
    dst[1][0] = *(const s8v*)(p_ + 1024 + sx0); dst[1][1] = *(const s8v*)(p_ + 1024 + sx1); \
  } while (0)

  f4v acc[8][4];
#pragma unroll
  for (int m = 0; m < 8; ++m)
#pragma unroll
    for (int n = 0; n < 4; ++n) acc[m][n] = (f4v)0.0f;

  // prologue: c0 all 4 halves (buf0) + c1's Alo,Blo,Bhi (buf1).
  // VMW(6) drains the 8 c0 loads; c1's 6 stay in flight (= steady-state entry).
  STG(gA,        0, 0);
  STG(gA + k128, 0, 8192);
  STG(gB,        0, 16384);
  STG(gB + k128, 0, 24576);
  STG(gA,        64, 32768);          // Alo(c1)
  STG(gB,        64, 32768 + 16384);  // Blo(c1)
  STG(gB + k128, 64, 32768 + 24576);  // Bhi(c1)
  VMW(6);
  SBAR();

  s8v a0[4][2], a1[4][2], b0[2][2], b1[2][2];

  for (int i = 0; i < NITER; ++i) {
    const long w2 = (i == NITER - 1) ? -128L : 0L;   // wrap c0+2 dummy stages
    const long w3 = (i == NITER - 1) ? -192L : 0L;   // wrap c1+2 dummy stages
    // ---- P1: pre {aLo,bL,bH}(c0); STG Ahi(c1); MM Q00 ----
    RDA(a0, 0, 0); RDB(b0, 0, 0); RDB(b1, 1, 0);
    STG(gA + k128, 64, 32768 + 8192);
    SBAR(); mmq<0, 0>(acc, a0, b0);
    // ---- P2: MM Q01; post-read aHi(c0) ----
    SBAR(); mmq<0, 1>(acc, a0, b1);
    RDA(a1, 1, 0);
    // ---- P3: STG Alo+Blo(c0+2); MM Q10 ----
    STG(gA, 128 + w2, 0);
    STG(gB, 128 + w2, 16384);
    SBAR(); mmq<1, 0>(acc, a1, b0);
    // ---- P4: STG Bhi(c0+2); MM Q11; VMW(6) pub c1 ----
    STG(gB + k128, 128 + w2, 24576);
    SBAR(); mmq<1, 1>(acc, a1, b1);
    VMW(6); SBAR();
    // ---- P5: pre {aLo,bL,bH}(c1); STG Ahi(c0+2); MM Q00 ----
    RDA(a0, 0, 32768); RDB(b0, 0, 32768); RDB(b1, 1, 32768);
    STG(gA + k128, 128 + w2, 8192);
    SBAR(); mmq<0, 0>(acc, a0, b0);
    // ---- P6: MM Q01; post-read aHi(c1) ----
    SBAR(); mmq<0, 1>(acc, a0, b1);
    RDA(a1, 1, 32768);
    // ---- P7: STG Alo+Blo(c1+2); MM Q10 ----
    STG(gA, 192 + w3, 32768);
    STG(gB, 192 + w3, 32768 + 16384);
    SBAR(); mmq<1, 0>(acc, a1, b0);
    // ---- P8: STG Bhi(c1+2); MM Q11; VMW(6) pub c0+2 ----
    STG(gB + k128, 192 + w3, 32768 + 24576);
    SBAR(); mmq<1, 1>(acc, a1, b1);
    VMW(6); SBAR();

    gA += 128; gB += 128;
  }
  VMW(0);          // drain remaining dummy prefetches

  // ---- epilogue: row = bm + mq*128 + wm*64 + mi*16 + ks*4 + r ; col = bn + nq*128 + wn*32 + ni*16 + fr
#pragma unroll
  for (int mq = 0; mq < 2; ++mq)
#pragma unroll
    for (int mi = 0; mi < 4; ++mi)
#pragma unroll
      for (int nq = 0; nq < 2; ++nq)
#pragma unroll
        for (int ni = 0; ni < 2; ++ni) {
          const size_t row0 = bm + mq * 128 + wm * 64 + mi * 16 + ks * 4;
          const size_t col  = bn + nq * 128 + wn * 32 + ni * 16 + fr;
          float* cp = C + row0 * (size_t)N + col;
          f4v v = acc[mq * 4 + mi][nq * 2 + ni];
          cp[0] = v[0]; cp[N] = v[1]; cp[2 * (size_t)N] = v[2]; cp[3 * (size_t)N] = v[3];
        }
#undef STG
#undef RDA
#undef RDB
}

// ---------- launch ----------
extern "C" void kernel_launch(void* const* d_in, const int* in_sizes, int n_in,
                              void* d_out, int out_size, void* d_ws, size_t ws_size,
                              hipStream_t stream) {
  const float* x  = (const float*)d_in[0];   // [8192,4096]
  const float* c0 = (const float*)d_in[1];   // [1,16,16,64]
  const float* c1 = (const float*)d_in[2];   // [64,16,16,64]
  const float* c2 = (const float*)d_in[3];   // [64,16,16,1]
  float* out = (float*)d_out;                // [8192,4096] fp32

  char* ws = (char*)d_ws;
  unsigned short* T   = (unsigned short*)ws;                      // 8 MB  bf16
  unsigned short* c2t = (unsigned short*)(ws + (8u << 20));       // 32 KB bf16
  unsigned short* Wb  = (unsigned short*)(ws + (16u << 20));      // 32 MB bf16
  unsigned short* xb  = (unsigned short*)(ws + (48u << 20));      // 64 MB bf16

  hipLaunchKernelGGL(cast_bf16,  dim3(16384), dim3(256), 0, stream, x, xb);
  hipLaunchKernelGGL(contract1b, dim3(4096),  dim3(256), 0, stream, c0, c1, T);
  hipLaunchKernelGGL(transc2,    dim3(16),    dim3(256), 0, stream, c2, c2t);
  hipLaunchKernelGGL(buildW3,    dim3(256),   dim3(256), 0, stream, T, c2t, Wb);
  hipLaunchKernelGGL(gemm8,      dim3(512),   dim3(512), 0, stream, xb, Wb, out);
}